// Round 6
// baseline (5237.302 us; speedup 1.0000x reference)
//
#include <hip/hip_runtime.h>
#include <hip/hip_bf16.h>

#define BATCH 64
#define SEQ   512
#define ISZ   1024
#define HID   1024
#define OUTSEQ_ELEMS (BATCH * SEQ * HID)   // 33554432
#define NGRP  2              // independent batch groups (32 batches each)
#define NCB   16             // col-blocks per group
#define GB    32             // batches per group
#define BCOLS 64             // hidden cols per block
#define NBLK  (NGRP * NCB)   // 32 blocks
#define FSTR  16             // flag stride in u32 (64 B)

typedef float f32x4 __attribute__((ext_vector_type(4)));
typedef short bf16x8 __attribute__((ext_vector_type(8)));

__device__ __forceinline__ unsigned short f2bf(float f) {
    union { float f; unsigned u; } v; v.f = f;
    unsigned r = v.u + 0x7fffu + ((v.u >> 16) & 1u);   // RNE
    return (unsigned short)(r >> 16);
}

// ---------------------------------------------------------------------------
// Kernel A: xp[m][n] = input[m][:] . Wx[:][n] + b[n]  -> written into d_out.
// (unchanged since R1 — proven, ~180 us)
// ---------------------------------------------------------------------------
__global__ __launch_bounds__(256)
void xproj_gemm(const float* __restrict__ A, const float* __restrict__ W,
                const float* __restrict__ bias, float* __restrict__ C)
{
    __shared__ __align__(16) unsigned short As[128][72];
    __shared__ __align__(16) unsigned short Bs[128][72];
    const int tid  = threadIdx.x;
    const int lane = tid & 63;
    const int wave = tid >> 6;
    const int m0 = blockIdx.y * 128;
    const int n0 = blockIdx.x * 128;
    const int wm = (wave >> 1) * 64;
    const int wn = (wave & 1) * 64;
    const int l15 = lane & 15;
    const int kq8 = (lane >> 4) * 8;

    f32x4 acc[4][4] = {};

    for (int k0 = 0; k0 < ISZ; k0 += 64) {
        #pragma unroll
        for (int i = 0; i < 8; ++i) {
            int idx = tid + i * 256;
            int row = idx >> 4;
            int kq  = idx & 15;
            float4 v = *reinterpret_cast<const float4*>(
                A + (size_t)(m0 + row) * ISZ + k0 + kq * 4);
            unsigned short* dst = &As[row][kq * 4];
            dst[0] = f2bf(v.x); dst[1] = f2bf(v.y);
            dst[2] = f2bf(v.z); dst[3] = f2bf(v.w);
        }
        #pragma unroll
        for (int i = 0; i < 8; ++i) {
            int idx = tid + i * 256;
            int kk = idx >> 5;
            int nq = idx & 31;
            float4 v = *reinterpret_cast<const float4*>(
                W + (size_t)(k0 + kk) * HID + n0 + nq * 4);
            Bs[nq * 4 + 0][kk] = f2bf(v.x);
            Bs[nq * 4 + 1][kk] = f2bf(v.y);
            Bs[nq * 4 + 2][kk] = f2bf(v.z);
            Bs[nq * 4 + 3][kk] = f2bf(v.w);
        }
        __syncthreads();
        #pragma unroll
        for (int kk = 0; kk < 64; kk += 32) {
            const int krd = kk + kq8;
            bf16x8 a[4], b[4];
            #pragma unroll
            for (int mf = 0; mf < 4; ++mf)
                a[mf] = *reinterpret_cast<const bf16x8*>(&As[wm + mf * 16 + l15][krd]);
            #pragma unroll
            for (int nf = 0; nf < 4; ++nf)
                b[nf] = *reinterpret_cast<const bf16x8*>(&Bs[wn + nf * 16 + l15][krd]);
            #pragma unroll
            for (int mf = 0; mf < 4; ++mf)
                #pragma unroll
                for (int nf = 0; nf < 4; ++nf)
                    acc[mf][nf] = __builtin_amdgcn_mfma_f32_16x16x32_bf16(
                        a[mf], b[nf], acc[mf][nf], 0, 0, 0);
        }
        __syncthreads();
    }

    const int r4 = (lane >> 4) * 4;
    #pragma unroll
    for (int nf = 0; nf < 4; ++nf) {
        int col = n0 + wn + nf * 16 + l15;
        float bv = bias[col];
        #pragma unroll
        for (int mf = 0; mf < 4; ++mf) {
            int row = m0 + wm + mf * 16 + r4;
            #pragma unroll
            for (int r = 0; r < 4; ++r)
                C[(size_t)(row + r) * HID + col] = acc[mf][nf][r] + bv;
        }
    }
}

// ---------------------------------------------------------------------------
// Kernel B: proven R2 sync semantics (plain h stores -> syncthreads drain ->
// RELEASE flag; RELAXED poll -> ACQUIRE fence), new geometry:
//   2 independent batch-groups x 16 col-blocks; block = 32 batches x 64 cols.
//   - per-block h read/step: 64 KB (was 128 KB)
//   - fencing blocks: 32 (was 64); flags polled per group: 16 (was 64)
//   - Wh slice resident in 132 KB LDS
//   - fp32 out stores write-through (sc0 sc1): no cross-block reader, and it
//     empties most of the release-wbl2 dirty payload. h stores stay PLAIN.
// ---------------------------------------------------------------------------
__global__ __launch_bounds__(512, 1)
void rnn_steps(const float* __restrict__ W, const float* __restrict__ h0,
               float* __restrict__ out,
               unsigned short* __restrict__ hA, unsigned short* __restrict__ hB,
               unsigned int* __restrict__ flags)
{
    __shared__ __align__(16) unsigned short Bsh[BCOLS][1032];   // 132 KB
    const int tid  = threadIdx.x;
    const int lane = tid & 63;
    const int wave = tid >> 6;
    const int g  = blockIdx.x >> 4;        // batch group 0..1
    const int cb = blockIdx.x & 15;        // col-block 0..15
    const int c0 = cb * BCOLS;
    const int mt = wave >> 2;              // M-tile (batches 16*mt..+16)
    const int nt = wave & 3;               // N-tile (cols 16*nt..+16)
    const int l15 = lane & 15;
    const int kq8 = (lane >> 4) * 8;

    // ---- stage Wh cols [c0, c0+64) -> Bsh[col][k] bf16 (once) ----
    for (int idx = tid; idx < 16 * 1024; idx += 512) {
        int k  = idx >> 4;
        int c4 = (idx & 15) * 4;
        float4 v = *reinterpret_cast<const float4*>(
            W + (size_t)(ISZ + k) * HID + c0 + c4);
        Bsh[c4 + 0][k] = f2bf(v.x);
        Bsh[c4 + 1][k] = f2bf(v.y);
        Bsh[c4 + 2][k] = f2bf(v.z);
        Bsh[c4 + 3][k] = f2bf(v.w);
    }
    // ---- init h_0 rows [32g,32g+32) x cols [c0,c0+64) -> hA (plain) ----
    {
        int b  = tid >> 4;                 // 0..31
        int c4 = (tid & 15) * 4;
        float4 v = *reinterpret_cast<const float4*>(
            h0 + (size_t)(g * GB + b) * HID + c0 + c4);
        unsigned short* p = hA + (size_t)(g * GB + b) * HID + c0 + c4;
        p[0] = f2bf(v.x); p[1] = f2bf(v.y); p[2] = f2bf(v.z); p[3] = f2bf(v.w);
    }
    __syncthreads();   // drains init stores to L2
    if (tid == 0)
        __hip_atomic_store(flags + (g * NCB + cb) * FSTR, 1u,
                           __ATOMIC_RELEASE, __HIP_MEMORY_SCOPE_AGENT);

    unsigned int* gfl = flags + g * NCB * FSTR;
    const int arowg = g * GB + mt * 16 + l15;           // A-operand global row
    const unsigned short* ab0 = hA + (size_t)arowg * HID + kq8;
    const unsigned short* ab1 = hB + (size_t)arowg * HID + kq8;
    const int orow = g * GB + mt * 16 + (lane >> 4) * 4; // output batch base
    const int gcol = c0 + nt * 16 + l15;                 // output column
    const unsigned short* bbase = &Bsh[nt * 16 + l15][kq8];

    float xpv[4];
    #pragma unroll
    for (int j = 0; j < 4; ++j)
        xpv[j] = out[(size_t)(orow + j) * (SEQ * HID) + gcol];

    for (int t = 0; t < SEQ; ++t) {
        // ---- wait: all 16 group flags >= t+1, then acquire ----
        if (wave == 0) {
            int guard = 0;
            for (;;) {
                unsigned v = (lane < NCB)
                    ? __hip_atomic_load(gfl + lane * FSTR, __ATOMIC_RELAXED,
                                        __HIP_MEMORY_SCOPE_AGENT)
                    : 0xFFFFFFFFu;
                if (__all(v >= (unsigned)(t + 1))) break;
                if (++guard > (1 << 20)) break;   // degrade, never hang
                __builtin_amdgcn_s_sleep(1);
            }
            __builtin_amdgcn_fence(__ATOMIC_ACQUIRE, "agent");
        }
        __syncthreads();

        const unsigned short* ap = (t & 1) ? ab1 : ab0;
        unsigned short*       nx = (t & 1) ? hA : hB;

        bf16x8 Af[32];
        #pragma unroll
        for (int ks = 0; ks < 32; ++ks)
            Af[ks] = *reinterpret_cast<const bf16x8*>(ap + ks * 32);

        f32x4 ac0 = {}, ac1 = {}, ac2 = {}, ac3 = {};
        #pragma unroll
        for (int ks = 0; ks < 32; ks += 4) {
            bf16x8 b0 = *reinterpret_cast<const bf16x8*>(bbase + (ks + 0) * 32);
            bf16x8 b1 = *reinterpret_cast<const bf16x8*>(bbase + (ks + 1) * 32);
            bf16x8 b2 = *reinterpret_cast<const bf16x8*>(bbase + (ks + 2) * 32);
            bf16x8 b3 = *reinterpret_cast<const bf16x8*>(bbase + (ks + 3) * 32);
            ac0 = __builtin_amdgcn_mfma_f32_16x16x32_bf16(Af[ks + 0], b0, ac0, 0, 0, 0);
            ac1 = __builtin_amdgcn_mfma_f32_16x16x32_bf16(Af[ks + 1], b1, ac1, 0, 0, 0);
            ac2 = __builtin_amdgcn_mfma_f32_16x16x32_bf16(Af[ks + 2], b2, ac2, 0, 0, 0);
            ac3 = __builtin_amdgcn_mfma_f32_16x16x32_bf16(Af[ks + 3], b3, ac3, 0, 0, 0);
        }
        f32x4 acc = (ac0 + ac1) + (ac2 + ac3);

        float hv[4];
        #pragma unroll
        for (int j = 0; j < 4; ++j)
            hv[j] = tanhf(acc[j] + xpv[j]);

        // ---- h stores: PLAIN (flushed by the release wbl2 — proven path) ----
        #pragma unroll
        for (int j = 0; j < 4; ++j)
            nx[(size_t)(orow + j) * HID + gcol] = f2bf(hv[j]);

        if (t < SEQ - 1) {
            __syncthreads();   // all waves' h stores drained to L2
            if (tid == 0)
                __hip_atomic_store(gfl + cb * FSTR, (unsigned)(t + 2),
                                   __ATOMIC_RELEASE, __HIP_MEMORY_SCOPE_AGENT);
        }

        // ---- fp32 outputs: write-through (no cross-block reader) ----
        #pragma unroll
        for (int j = 0; j < 4; ++j) {
            float* p = out + (size_t)(orow + j) * (SEQ * HID)
                           + (size_t)t * HID + gcol;
            asm volatile("global_store_dword %0, %1, off sc0 sc1"
                         :: "v"(p), "v"(hv[j]) : "memory");
        }
        if (t == SEQ - 1) {
            #pragma unroll
            for (int j = 0; j < 4; ++j) {
                float* p = out + (size_t)OUTSEQ_ELEMS
                               + (size_t)(orow + j) * HID + gcol;
                asm volatile("global_store_dword %0, %1, off sc0 sc1"
                             :: "v"(p), "v"(hv[j]) : "memory");
            }
        } else {
            // prefetch xp[t+1] into registers (survives next step's inv)
            #pragma unroll
            for (int j = 0; j < 4; ++j)
                xpv[j] = out[(size_t)(orow + j) * (SEQ * HID)
                             + (size_t)(t + 1) * HID + gcol];
        }
    }
}

extern "C" void kernel_launch(void* const* d_in, const int* in_sizes, int n_in,
                              void* d_out, int out_size, void* d_ws, size_t ws_size,
                              hipStream_t stream)
{
    const float* input = (const float*)d_in[0];
    const float* h0    = (const float*)d_in[1];
    const float* W     = (const float*)d_in[2];
    const float* bias  = (const float*)d_in[3];
    float* out = (float*)d_out;

    unsigned short* hA = (unsigned short*)d_ws;
    unsigned short* hB = hA + (size_t)BATCH * HID;
    unsigned int* flags =
        (unsigned int*)((char*)d_ws + (size_t)2 * BATCH * HID * sizeof(unsigned short));

    dim3 gA(HID / 128, (BATCH * SEQ) / 128);   // (8, 256)
    xproj_gemm<<<gA, dim3(256), 0, stream>>>(input, W, bias, out);

    hipMemsetAsync(flags, 0, NBLK * FSTR * sizeof(unsigned int), stream);

    rnn_steps<<<dim3(NBLK), dim3(512), 0, stream>>>(W, h0, out, hA, hB, flags);
}